// Round 3
// baseline (290.434 us; speedup 1.0000x reference)
//
#include <hip/hip_runtime.h>

#define SQ   2048
#define DD   64
#define BK   64
#define BQ   128
#define LDW  72
#define NT   32           // SQ / BK
#define BUFH (BK * LDW)   // halves per LDS buffer (4608)

typedef _Float16 f16x8 __attribute__((ext_vector_type(8)));
typedef _Float16 f16x4 __attribute__((ext_vector_type(4)));
typedef _Float16 f16x2 __attribute__((ext_vector_type(2)));
typedef float    f32x4 __attribute__((ext_vector_type(4)));

#if __has_builtin(__builtin_amdgcn_exp2f)
#define EXP2F(x) __builtin_amdgcn_exp2f(x)
#else
#define EXP2F(x) exp2f(x)
#endif

// __builtin_amdgcn_cvt_pkrtz returns __fp16x2; bit-cast to our _Float16x2.
static __device__ __forceinline__ f16x2 PKRTZ(float a, float b) {
    typedef __fp16 fp16x2_t __attribute__((ext_vector_type(2)));
    union { fp16x2_t i; f16x2 o; } u;
    u.i = __builtin_amdgcn_cvt_pkrtz(a, b);
    return u.o;
}
#define MFMA32(a, b, c) __builtin_amdgcn_mfma_f32_16x16x32_f16((a), (b), (c), 0, 0, 0)

// 512 threads = 8 waves: wave (qw = w&3, kh = w>>2) owns q-rows [qw*32, qw*32+32)
// and key half [kh*32, kh*32+32) of every 64-key tile. 16 waves/CU (2 blocks).
__global__ __launch_bounds__(512, 4)
void attn_fused4(const float* __restrict__ Qg,
                 const float* __restrict__ Kg,
                 const float* __restrict__ Vg,
                 const unsigned char* __restrict__ maskg,
                 float* __restrict__ Og)
{
    __shared__ __align__(16) _Float16 smem[4 * BUFH];   // Kl[2] | Vt[2] = 36864 B

    const int tid  = threadIdx.x;
    const int lane = tid & 63;
    const int w    = tid >> 6;       // 0..7
    const int quad = lane >> 4;
    const int l16  = lane & 15;
    const int qw   = w & 3;          // q row-group
    const int kh   = w >> 2;         // key half

    // XCD swizzle: all 16 q-tiles of one (b,h) land on one XCD -> K/V L2 reuse.
    const int n     = blockIdx.x;            // 512 blocks
    const int bh    = (n & 7) + 8 * ((n >> 3) & 3);
    const int qtile = n >> 5;                // 0..15
    const int qBase = qtile * BQ;

    // dk = key length (2048). Fold log2(e) into the scale so exp(x) == exp2(x').
    const float QSCALE = 0.02209708691207961f * 1.4426950408889634f;
    const float MASKED = -1e10f * (0.02209708691207961f * 1.4426950408889634f);

    // ---- Q fragments, pre-scaled: rows qBase + qw*32 + qg*16 + l16 ----
    f16x8 qf[2][2];
#pragma unroll
    for (int qg = 0; qg < 2; ++qg) {
        const float* qrow = Qg + ((size_t)bh * SQ + qBase + qw * 32 + qg * 16 + l16) * DD;
#pragma unroll
        for (int h = 0; h < 2; ++h) {
            float4 a = *(const float4*)(qrow + h * 32 + quad * 8);
            float4 b = *(const float4*)(qrow + h * 32 + quad * 8 + 4);
            union { f16x8 v; f16x2 p[4]; } u;
            u.p[0] = PKRTZ(a.x * QSCALE, a.y * QSCALE);
            u.p[1] = PKRTZ(a.z * QSCALE, a.w * QSCALE);
            u.p[2] = PKRTZ(b.x * QSCALE, b.y * QSCALE);
            u.p[3] = PKRTZ(b.z * QSCALE, b.w * QSCALE);
            qf[qg][h] = u.v;
        }
    }

    f32x4 acc[2][4];   // [qg][dt] partial over this wave's key half
#pragma unroll
    for (int qg = 0; qg < 2; ++qg)
#pragma unroll
        for (int d = 0; d < 4; ++d) acc[qg][d] = (f32x4){0.f, 0.f, 0.f, 0.f};
    float lsum[2] = {0.f, 0.f};

    // staging: waves 0-3 stage K (same map as before at 256t), waves 4-7 stage V
    const bool isK = tid < 256;
    const int t2   = tid & 255;
    const int sr   = t2 >> 2;             // K row 0..63
    const int sc4  = (t2 & 3) * 16;       // K col chunk
    const int vq   = t2 & 15;             // V key-quad
    const int vdb  = (t2 >> 4) * 4;       // V d block
    const int ctw  = vq >> 2, qdw = vq & 3;
    const int keyp = (ctw >> 1) * 32 + qdw * 8 + (ctw & 1) * 4;  // frag-major key'

    const float* Kbase = Kg + (size_t)bh * SQ * DD;
    const float* Vbase = Vg + (size_t)bh * SQ * DD;
    // mask: each wave loads exactly its own 32 rows x 32 keys quarter -> per-wave __any gate
    const unsigned char* mbase = maskg
        + (size_t)(qBase + qw * 32 + (lane >> 1)) * SQ + kh * 32 + (lane & 1) * 16;

    // ---- prologue: stage tile 0 ----
    if (isK) {
        const float* ks = Kbase + (size_t)sr * DD + sc4;
        float4 x0 = *(const float4*)(ks),     x1 = *(const float4*)(ks + 4);
        float4 x2 = *(const float4*)(ks + 8), x3 = *(const float4*)(ks + 12);
        union { f16x8 v; f16x2 p[4]; } y0, y1;
        y0.p[0] = PKRTZ(x0.x, x0.y); y0.p[1] = PKRTZ(x0.z, x0.w);
        y0.p[2] = PKRTZ(x1.x, x1.y); y0.p[3] = PKRTZ(x1.z, x1.w);
        y1.p[0] = PKRTZ(x2.x, x2.y); y1.p[1] = PKRTZ(x2.z, x2.w);
        y1.p[2] = PKRTZ(x3.x, x3.y); y1.p[3] = PKRTZ(x3.z, x3.w);
        *(f16x8*)&smem[sr * LDW + sc4]     = y0.v;
        *(f16x8*)&smem[sr * LDW + sc4 + 8] = y1.v;
    } else {
        const float* vb = Vbase + (size_t)(vq * 4) * DD + vdb;
        float4 v0 = *(const float4*)(vb);
        float4 v1 = *(const float4*)(vb + DD);
        float4 v2 = *(const float4*)(vb + 2 * DD);
        float4 v3 = *(const float4*)(vb + 3 * DD);
        _Float16* VT = smem + 2 * BUFH;
        union { f16x4 v; f16x2 p[2]; } t;
        t.p[0] = PKRTZ(v0.x, v1.x); t.p[1] = PKRTZ(v2.x, v3.x);
        *(f16x4*)&VT[(vdb + 0) * LDW + keyp] = t.v;
        t.p[0] = PKRTZ(v0.y, v1.y); t.p[1] = PKRTZ(v2.y, v3.y);
        *(f16x4*)&VT[(vdb + 1) * LDW + keyp] = t.v;
        t.p[0] = PKRTZ(v0.z, v1.z); t.p[1] = PKRTZ(v2.z, v3.z);
        *(f16x4*)&VT[(vdb + 2) * LDW + keyp] = t.v;
        t.p[0] = PKRTZ(v0.w, v1.w); t.p[1] = PKRTZ(v2.w, v3.w);
        *(f16x4*)&VT[(vdb + 3) * LDW + keyp] = t.v;
    }
    uint4 ma = *(const uint4*)mbase;
    int tm = __any((int)(ma.x | ma.y | ma.z | ma.w));
    __syncthreads();

#pragma unroll 2
    for (int kt = 0; kt < NT; ++kt) {
        const int cur = kt & 1;
        const bool more = (kt + 1 < NT);
        _Float16* Kc = smem + cur * BUFH;
        _Float16* Vc = smem + 2 * BUFH + cur * BUFH;

        // ---- register prefetch of next tile (K xor V per wave role) ----
        float4 x0, x1, x2, x3;
        uint4 ma2 = {0u, 0u, 0u, 0u};
        if (more) {
            const int k0n = (kt + 1) * BK;
            if (isK) {
                const float* ks = Kbase + (size_t)(k0n + sr) * DD + sc4;
                x0 = *(const float4*)(ks);     x1 = *(const float4*)(ks + 4);
                x2 = *(const float4*)(ks + 8); x3 = *(const float4*)(ks + 12);
            } else {
                const float* vb = Vbase + (size_t)(k0n + vq * 4) * DD + vdb;
                x0 = *(const float4*)(vb);          x1 = *(const float4*)(vb + DD);
                x2 = *(const float4*)(vb + 2 * DD); x3 = *(const float4*)(vb + 3 * DD);
            }
            ma2 = *(const uint4*)(mbase + k0n);
        }

        // ---- S^T = K*Q^T over this wave's 32-key half (4 ds_reads, 8 MFMA) ----
        f32x4 sA[2][2];   // [qg][c]: keys kh*32 + c*16 + quad*4 + r, q = l16
#pragma unroll
        for (int c = 0; c < 2; ++c) {
            const int krow = (kh * 2 + c) * 16 + l16;
            f16x8 kf0 = *(const f16x8*)&Kc[krow * LDW + quad * 8];
            f16x8 kf1 = *(const f16x8*)&Kc[krow * LDW + 32 + quad * 8];
#pragma unroll
            for (int qg = 0; qg < 2; ++qg) {
                f32x4 cc = (f32x4){0.f, 0.f, 0.f, 0.f};
                cc = MFMA32(kf0, qf[qg][0], cc);
                cc = MFMA32(kf1, qf[qg][1], cc);
                sA[qg][c] = cc;
            }
        }

        // ---- mask (rare slow path; tm is per-wave and covers exactly our quarter) ----
        if (tm) {
#pragma unroll
            for (int qg = 0; qg < 2; ++qg) {
                const size_t qq = (size_t)(qBase + qw * 32 + qg * 16 + l16) * SQ;
#pragma unroll
                for (int c = 0; c < 2; ++c)
#pragma unroll
                    for (int r = 0; r < 4; ++r) {
                        const int kg = kt * BK + kh * 32 + c * 16 + quad * 4 + r;
                        if (maskg[qq + kg]) sA[qg][c][r] = MASKED;
                    }
            }
        }

        // ---- softmax numerators: raw exp2 (log2e folded into QSCALE), packed cvt ----
        union { f16x8 v; f16x2 p[4]; } pf[2];
#pragma unroll
        for (int qg = 0; qg < 2; ++qg) {
            float e0 = EXP2F(sA[qg][0][0]), e1 = EXP2F(sA[qg][0][1]);
            float e2 = EXP2F(sA[qg][0][2]), e3 = EXP2F(sA[qg][0][3]);
            float e4 = EXP2F(sA[qg][1][0]), e5 = EXP2F(sA[qg][1][1]);
            float e6 = EXP2F(sA[qg][1][2]), e7 = EXP2F(sA[qg][1][3]);
            lsum[qg] += ((e0 + e1) + (e2 + e3)) + ((e4 + e5) + (e6 + e7));
            pf[qg].p[0] = PKRTZ(e0, e1); pf[qg].p[1] = PKRTZ(e2, e3);
            pf[qg].p[2] = PKRTZ(e4, e5); pf[qg].p[3] = PKRTZ(e6, e7);
        }

        // ---- P*V with 16x16x32: Vt permutation already matches the x32 B-frag ----
#pragma unroll
        for (int dt = 0; dt < 4; ++dt) {
            f16x8 vv = *(const f16x8*)&Vc[(dt * 16 + l16) * LDW + kh * 32 + quad * 8];
            acc[0][dt] = MFMA32(pf[0].v, vv, acc[0][dt]);
            acc[1][dt] = MFMA32(pf[1].v, vv, acc[1][dt]);
        }

        // ---- stage prefetched tile into the other buffer ----
        if (more) {
            _Float16* Kn = smem + (cur ^ 1) * BUFH;
            _Float16* Vn = smem + 2 * BUFH + (cur ^ 1) * BUFH;
            if (isK) {
                union { f16x8 v; f16x2 p[4]; } y0, y1;
                y0.p[0] = PKRTZ(x0.x, x0.y); y0.p[1] = PKRTZ(x0.z, x0.w);
                y0.p[2] = PKRTZ(x1.x, x1.y); y0.p[3] = PKRTZ(x1.z, x1.w);
                y1.p[0] = PKRTZ(x2.x, x2.y); y1.p[1] = PKRTZ(x2.z, x2.w);
                y1.p[2] = PKRTZ(x3.x, x3.y); y1.p[3] = PKRTZ(x3.z, x3.w);
                *(f16x8*)&Kn[sr * LDW + sc4]     = y0.v;
                *(f16x8*)&Kn[sr * LDW + sc4 + 8] = y1.v;
            } else {
                union { f16x4 v; f16x2 p[2]; } t;
                t.p[0] = PKRTZ(x0.x, x1.x); t.p[1] = PKRTZ(x2.x, x3.x);
                *(f16x4*)&Vn[(vdb + 0) * LDW + keyp] = t.v;
                t.p[0] = PKRTZ(x0.y, x1.y); t.p[1] = PKRTZ(x2.y, x3.y);
                *(f16x4*)&Vn[(vdb + 1) * LDW + keyp] = t.v;
                t.p[0] = PKRTZ(x0.z, x1.z); t.p[1] = PKRTZ(x2.z, x3.z);
                *(f16x4*)&Vn[(vdb + 2) * LDW + keyp] = t.v;
                t.p[0] = PKRTZ(x0.w, x1.w); t.p[1] = PKRTZ(x2.w, x3.w);
                *(f16x4*)&Vn[(vdb + 3) * LDW + keyp] = t.v;
            }
        }
        // per-wave mask gate for next tile; single plain barrier per iter
        tm = __any((int)(ma2.x | ma2.y | ma2.z | ma2.w));
        __syncthreads();
    }

    // ---- epilogue: merge the two key-half partials via LDS, normalize, store ----
    float* M = (float*)smem;   // 8 (qw,qg) slots x 4 dt x 64 lanes x f32x4 = 32 KB, + lsum
    const int slot = qw * 2;
    if (kh) {
#pragma unroll
        for (int qg = 0; qg < 2; ++qg) {
#pragma unroll
            for (int dt = 0; dt < 4; ++dt)
                *(f32x4*)&M[(((slot + qg) * 4 + dt) * 64 + lane) * 4] = acc[qg][dt];
            M[8192 + (slot + qg) * 64 + lane] = lsum[qg];
        }
    }
    __syncthreads();
    if (!kh) {
#pragma unroll
        for (int qg = 0; qg < 2; ++qg) {
#pragma unroll
            for (int dt = 0; dt < 4; ++dt)
                acc[qg][dt] += *(const f32x4*)&M[(((slot + qg) * 4 + dt) * 64 + lane) * 4];
            float l = lsum[qg] + M[8192 + (slot + qg) * 64 + lane];
            l += __shfl_xor(l, 16);
            l += __shfl_xor(l, 32);
            float* ob = Og + ((size_t)bh * SQ + qBase + qw * 32 + qg * 16) * DD;
#pragma unroll
            for (int r = 0; r < 4; ++r) {
                const float inv = 1.0f / __shfl(l, quad * 4 + r);
                const int qr = quad * 4 + r;
#pragma unroll
                for (int dt = 0; dt < 4; ++dt)
                    ob[qr * DD + dt * 16 + l16] = acc[qg][dt][r] * inv;
            }
        }
    }
}

extern "C" void kernel_launch(void* const* d_in, const int* in_sizes, int n_in,
                              void* d_out, int out_size, void* d_ws, size_t ws_size,
                              hipStream_t stream) {
    const float* Q = (const float*)d_in[0];
    const float* K = (const float*)d_in[1];
    const float* V = (const float*)d_in[2];
    const unsigned char* mask = (const unsigned char*)d_in[3];
    float* Out = (float*)d_out;
    attn_fused4<<<dim3(32 * 16), dim3(512), 0, stream>>>(Q, K, V, mask, Out);
}

// Round 4
// 288.842 us; speedup vs baseline: 1.0055x; 1.0055x over previous
//
#include <hip/hip_runtime.h>

#define SQ   2048
#define DD   64
#define BK   64
#define BQ   128
#define LDW  72
#define NT   32           // SQ / BK
#define BUFH (BK * LDW)   // halves per LDS buffer (4608)

typedef _Float16 f16x8 __attribute__((ext_vector_type(8)));
typedef _Float16 f16x4 __attribute__((ext_vector_type(4)));
typedef _Float16 f16x2 __attribute__((ext_vector_type(2)));
typedef float    f32x4 __attribute__((ext_vector_type(4)));

#if __has_builtin(__builtin_amdgcn_exp2f)
#define EXP2F(x) __builtin_amdgcn_exp2f(x)
#else
#define EXP2F(x) exp2f(x)
#endif

// __builtin_amdgcn_cvt_pkrtz returns __fp16x2; bit-cast to our _Float16x2.
static __device__ __forceinline__ f16x2 PKRTZ(float a, float b) {
    typedef __fp16 fp16x2_t __attribute__((ext_vector_type(2)));
    union { fp16x2_t i; f16x2 o; } u;
    u.i = __builtin_amdgcn_cvt_pkrtz(a, b);
    return u.o;
}
#define MFMA32(a, b, c) __builtin_amdgcn_mfma_f32_16x16x32_f16((a), (b), (c), 0, 0, 0)

// 512 threads = 8 waves: wave (qw = w&3, kh = w>>2) owns q-rows [qw*32, qw*32+32)
// and key half [kh*32, kh*32+32) of every 64-key tile. 16 waves/CU (2 blocks).
// waves_per_eu(4,4): pin VGPR budget at 128 — R3 showed min-only bounds let the
// allocator squeeze to the 64-VGPR tier and spill the prefetch regs to scratch.
__global__ __attribute__((amdgpu_waves_per_eu(4, 4))) __launch_bounds__(512)
void attn_fused5(const float* __restrict__ Qg,
                 const float* __restrict__ Kg,
                 const float* __restrict__ Vg,
                 const unsigned char* __restrict__ maskg,
                 float* __restrict__ Og)
{
    __shared__ __align__(16) _Float16 smem[4 * BUFH];   // Kl[2] | Vt[2] = 36864 B

    const int tid  = threadIdx.x;
    const int lane = tid & 63;
    const int w    = tid >> 6;       // 0..7
    const int quad = lane >> 4;
    const int l16  = lane & 15;
    const int qw   = w & 3;          // q row-group
    const int kh   = w >> 2;         // key half

    // XCD swizzle: all 16 q-tiles of one (b,h) land on one XCD -> K/V L2 reuse.
    const int n     = blockIdx.x;            // 512 blocks
    const int bh    = (n & 7) + 8 * ((n >> 3) & 3);
    const int qtile = n >> 5;                // 0..15
    const int qBase = qtile * BQ;

    // dk = key length (2048). Fold log2(e) into the scale so exp(x) == exp2(x').
    const float QSCALE = 0.02209708691207961f * 1.4426950408889634f;
    const float MASKED = -1e10f * (0.02209708691207961f * 1.4426950408889634f);

    // ---- Q fragments, pre-scaled: rows qBase + qw*32 + qg*16 + l16 ----
    f16x8 qf[2][2];
#pragma unroll
    for (int qg = 0; qg < 2; ++qg) {
        const float* qrow = Qg + ((size_t)bh * SQ + qBase + qw * 32 + qg * 16 + l16) * DD;
#pragma unroll
        for (int h = 0; h < 2; ++h) {
            float4 a = *(const float4*)(qrow + h * 32 + quad * 8);
            float4 b = *(const float4*)(qrow + h * 32 + quad * 8 + 4);
            union { f16x8 v; f16x2 p[4]; } u;
            u.p[0] = PKRTZ(a.x * QSCALE, a.y * QSCALE);
            u.p[1] = PKRTZ(a.z * QSCALE, a.w * QSCALE);
            u.p[2] = PKRTZ(b.x * QSCALE, b.y * QSCALE);
            u.p[3] = PKRTZ(b.z * QSCALE, b.w * QSCALE);
            qf[qg][h] = u.v;
        }
    }

    f32x4 acc[2][4];   // [qg][dt] partial over this wave's key half
#pragma unroll
    for (int qg = 0; qg < 2; ++qg)
#pragma unroll
        for (int d = 0; d < 4; ++d) acc[qg][d] = (f32x4){0.f, 0.f, 0.f, 0.f};
    float lsum[2] = {0.f, 0.f};

    // staging: waves 0-3 stage K (same map as before at 256t), waves 4-7 stage V
    const bool isK = tid < 256;
    const int t2   = tid & 255;
    const int sr   = t2 >> 2;             // K row 0..63
    const int sc4  = (t2 & 3) * 16;       // K col chunk
    const int vq   = t2 & 15;             // V key-quad
    const int vdb  = (t2 >> 4) * 4;       // V d block
    const int ctw  = vq >> 2, qdw = vq & 3;
    const int keyp = (ctw >> 1) * 32 + qdw * 8 + (ctw & 1) * 4;  // frag-major key'

    const float* Kbase = Kg + (size_t)bh * SQ * DD;
    const float* Vbase = Vg + (size_t)bh * SQ * DD;
    // mask: each wave loads exactly its own 32 rows x 32 keys quarter -> per-wave __any gate
    const unsigned char* mbase = maskg
        + (size_t)(qBase + qw * 32 + (lane >> 1)) * SQ + kh * 32 + (lane & 1) * 16;

    // ---- prologue: stage tile 0 ----
    if (isK) {
        const float* ks = Kbase + (size_t)sr * DD + sc4;
        float4 x0 = *(const float4*)(ks),     x1 = *(const float4*)(ks + 4);
        float4 x2 = *(const float4*)(ks + 8), x3 = *(const float4*)(ks + 12);
        union { f16x8 v; f16x2 p[4]; } y0, y1;
        y0.p[0] = PKRTZ(x0.x, x0.y); y0.p[1] = PKRTZ(x0.z, x0.w);
        y0.p[2] = PKRTZ(x1.x, x1.y); y0.p[3] = PKRTZ(x1.z, x1.w);
        y1.p[0] = PKRTZ(x2.x, x2.y); y1.p[1] = PKRTZ(x2.z, x2.w);
        y1.p[2] = PKRTZ(x3.x, x3.y); y1.p[3] = PKRTZ(x3.z, x3.w);
        *(f16x8*)&smem[sr * LDW + sc4]     = y0.v;
        *(f16x8*)&smem[sr * LDW + sc4 + 8] = y1.v;
    } else {
        const float* vb = Vbase + (size_t)(vq * 4) * DD + vdb;
        float4 v0 = *(const float4*)(vb);
        float4 v1 = *(const float4*)(vb + DD);
        float4 v2 = *(const float4*)(vb + 2 * DD);
        float4 v3 = *(const float4*)(vb + 3 * DD);
        _Float16* VT = smem + 2 * BUFH;
        union { f16x4 v; f16x2 p[2]; } t;
        t.p[0] = PKRTZ(v0.x, v1.x); t.p[1] = PKRTZ(v2.x, v3.x);
        *(f16x4*)&VT[(vdb + 0) * LDW + keyp] = t.v;
        t.p[0] = PKRTZ(v0.y, v1.y); t.p[1] = PKRTZ(v2.y, v3.y);
        *(f16x4*)&VT[(vdb + 1) * LDW + keyp] = t.v;
        t.p[0] = PKRTZ(v0.z, v1.z); t.p[1] = PKRTZ(v2.z, v3.z);
        *(f16x4*)&VT[(vdb + 2) * LDW + keyp] = t.v;
        t.p[0] = PKRTZ(v0.w, v1.w); t.p[1] = PKRTZ(v2.w, v3.w);
        *(f16x4*)&VT[(vdb + 3) * LDW + keyp] = t.v;
    }
    uint4 ma = *(const uint4*)mbase;
    int tm = __any((int)(ma.x | ma.y | ma.z | ma.w));
    __syncthreads();

#pragma unroll 2
    for (int kt = 0; kt < NT; ++kt) {
        const int cur = kt & 1;
        const bool more = (kt + 1 < NT);
        _Float16* Kc = smem + cur * BUFH;
        _Float16* Vc = smem + 2 * BUFH + cur * BUFH;

        // ---- register prefetch of next tile (K xor V per wave role) ----
        float4 x0, x1, x2, x3;
        uint4 ma2 = {0u, 0u, 0u, 0u};
        if (more) {
            const int k0n = (kt + 1) * BK;
            if (isK) {
                const float* ks = Kbase + (size_t)(k0n + sr) * DD + sc4;
                x0 = *(const float4*)(ks);     x1 = *(const float4*)(ks + 4);
                x2 = *(const float4*)(ks + 8); x3 = *(const float4*)(ks + 12);
            } else {
                const float* vb = Vbase + (size_t)(k0n + vq * 4) * DD + vdb;
                x0 = *(const float4*)(vb);          x1 = *(const float4*)(vb + DD);
                x2 = *(const float4*)(vb + 2 * DD); x3 = *(const float4*)(vb + 3 * DD);
            }
            ma2 = *(const uint4*)(mbase + k0n);
        }

        // ---- S^T = K*Q^T over this wave's 32-key half (4 ds_reads, 8 MFMA) ----
        f32x4 sA[2][2];   // [qg][c]: keys kh*32 + c*16 + quad*4 + r, q = l16
#pragma unroll
        for (int c = 0; c < 2; ++c) {
            const int krow = (kh * 2 + c) * 16 + l16;
            f16x8 kf0 = *(const f16x8*)&Kc[krow * LDW + quad * 8];
            f16x8 kf1 = *(const f16x8*)&Kc[krow * LDW + 32 + quad * 8];
#pragma unroll
            for (int qg = 0; qg < 2; ++qg) {
                f32x4 cc = (f32x4){0.f, 0.f, 0.f, 0.f};
                cc = MFMA32(kf0, qf[qg][0], cc);
                cc = MFMA32(kf1, qf[qg][1], cc);
                sA[qg][c] = cc;
            }
        }

        // ---- mask (rare slow path; tm is per-wave and covers exactly our quarter) ----
        if (tm) {
#pragma unroll
            for (int qg = 0; qg < 2; ++qg) {
                const size_t qq = (size_t)(qBase + qw * 32 + qg * 16 + l16) * SQ;
#pragma unroll
                for (int c = 0; c < 2; ++c)
#pragma unroll
                    for (int r = 0; r < 4; ++r) {
                        const int kg = kt * BK + kh * 32 + c * 16 + quad * 4 + r;
                        if (maskg[qq + kg]) sA[qg][c][r] = MASKED;
                    }
            }
        }

        // ---- softmax numerators: raw exp2 (log2e folded into QSCALE), packed cvt ----
        union { f16x8 v; f16x2 p[4]; } pf[2];
#pragma unroll
        for (int qg = 0; qg < 2; ++qg) {
            float e0 = EXP2F(sA[qg][0][0]), e1 = EXP2F(sA[qg][0][1]);
            float e2 = EXP2F(sA[qg][0][2]), e3 = EXP2F(sA[qg][0][3]);
            float e4 = EXP2F(sA[qg][1][0]), e5 = EXP2F(sA[qg][1][1]);
            float e6 = EXP2F(sA[qg][1][2]), e7 = EXP2F(sA[qg][1][3]);
            lsum[qg] += ((e0 + e1) + (e2 + e3)) + ((e4 + e5) + (e6 + e7));
            pf[qg].p[0] = PKRTZ(e0, e1); pf[qg].p[1] = PKRTZ(e2, e3);
            pf[qg].p[2] = PKRTZ(e4, e5); pf[qg].p[3] = PKRTZ(e6, e7);
        }

        // ---- P*V with 16x16x32: Vt permutation already matches the x32 B-frag ----
#pragma unroll
        for (int dt = 0; dt < 4; ++dt) {
            f16x8 vv = *(const f16x8*)&Vc[(dt * 16 + l16) * LDW + kh * 32 + quad * 8];
            acc[0][dt] = MFMA32(pf[0].v, vv, acc[0][dt]);
            acc[1][dt] = MFMA32(pf[1].v, vv, acc[1][dt]);
        }

        // ---- stage prefetched tile into the other buffer ----
        if (more) {
            _Float16* Kn = smem + (cur ^ 1) * BUFH;
            _Float16* Vn = smem + 2 * BUFH + (cur ^ 1) * BUFH;
            if (isK) {
                union { f16x8 v; f16x2 p[4]; } y0, y1;
                y0.p[0] = PKRTZ(x0.x, x0.y); y0.p[1] = PKRTZ(x0.z, x0.w);
                y0.p[2] = PKRTZ(x1.x, x1.y); y0.p[3] = PKRTZ(x1.z, x1.w);
                y1.p[0] = PKRTZ(x2.x, x2.y); y1.p[1] = PKRTZ(x2.z, x2.w);
                y1.p[2] = PKRTZ(x3.x, x3.y); y1.p[3] = PKRTZ(x3.z, x3.w);
                *(f16x8*)&Kn[sr * LDW + sc4]     = y0.v;
                *(f16x8*)&Kn[sr * LDW + sc4 + 8] = y1.v;
            } else {
                union { f16x4 v; f16x2 p[2]; } t;
                t.p[0] = PKRTZ(x0.x, x1.x); t.p[1] = PKRTZ(x2.x, x3.x);
                *(f16x4*)&Vn[(vdb + 0) * LDW + keyp] = t.v;
                t.p[0] = PKRTZ(x0.y, x1.y); t.p[1] = PKRTZ(x2.y, x3.y);
                *(f16x4*)&Vn[(vdb + 1) * LDW + keyp] = t.v;
                t.p[0] = PKRTZ(x0.z, x1.z); t.p[1] = PKRTZ(x2.z, x3.z);
                *(f16x4*)&Vn[(vdb + 2) * LDW + keyp] = t.v;
                t.p[0] = PKRTZ(x0.w, x1.w); t.p[1] = PKRTZ(x2.w, x3.w);
                *(f16x4*)&Vn[(vdb + 3) * LDW + keyp] = t.v;
            }
        }
        // per-wave mask gate for next tile; single plain barrier per iter
        tm = __any((int)(ma2.x | ma2.y | ma2.z | ma2.w));
        __syncthreads();
    }

    // ---- epilogue: merge the two key-half partials via LDS, normalize, store ----
    float* M = (float*)smem;   // 8 (qw,qg) slots x 4 dt x 64 lanes x f32x4 = 32 KB, + lsum
    const int slot = qw * 2;
    if (kh) {
#pragma unroll
        for (int qg = 0; qg < 2; ++qg) {
#pragma unroll
            for (int dt = 0; dt < 4; ++dt)
                *(f32x4*)&M[(((slot + qg) * 4 + dt) * 64 + lane) * 4] = acc[qg][dt];
            M[8192 + (slot + qg) * 64 + lane] = lsum[qg];
        }
    }
    __syncthreads();
    if (!kh) {
#pragma unroll
        for (int qg = 0; qg < 2; ++qg) {
#pragma unroll
            for (int dt = 0; dt < 4; ++dt)
                acc[qg][dt] += *(const f32x4*)&M[(((slot + qg) * 4 + dt) * 64 + lane) * 4];
            float l = lsum[qg] + M[8192 + (slot + qg) * 64 + lane];
            l += __shfl_xor(l, 16);
            l += __shfl_xor(l, 32);
            float* ob = Og + ((size_t)bh * SQ + qBase + qw * 32 + qg * 16) * DD;
#pragma unroll
            for (int r = 0; r < 4; ++r) {
                const float inv = 1.0f / __shfl(l, quad * 4 + r);
                const int qr = quad * 4 + r;
#pragma unroll
                for (int dt = 0; dt < 4; ++dt)
                    ob[qr * DD + dt * 16 + l16] = acc[qg][dt][r] * inv;
            }
        }
    }
}

extern "C" void kernel_launch(void* const* d_in, const int* in_sizes, int n_in,
                              void* d_out, int out_size, void* d_ws, size_t ws_size,
                              hipStream_t stream) {
    const float* Q = (const float*)d_in[0];
    const float* K = (const float*)d_in[1];
    const float* V = (const float*)d_in[2];
    const unsigned char* mask = (const unsigned char*)d_in[3];
    float* Out = (float*)d_out;
    attn_fused5<<<dim3(32 * 16), dim3(512), 0, stream>>>(Q, K, V, mask, Out);
}